// Round 2
// baseline (86.591 us; speedup 1.0000x reference)
//
#include <hip/hip_runtime.h>

// B=32, S=512, H=256, T=MAX_MEL=2000, DUR_MAX=8 (dur in [0,8))
// d_out: output [B,T,H] f32 then mel_len [B] as floats.
//
// R9: single-variable A/B vs R8 — NONTEMPORAL stores on the out stream.
//  R6 (nt) = 86.9 and R7 (plain, +early loads) = 88.2 never isolated this
//  knob; out (62.5 MiB) is write-once/read-never, 80% of kernel traffic.
//  nt keeps the store stream from thrashing the 4 MiB/XCD L2.
//  Everything else byte-identical to R8 (balanced LDS scatter, 1024 blocks).
constexpr int B_ = 32;
constexpr int S_ = 512;
constexpr int H_ = 256;
constexpr int T_ = 2000;
constexpr int F4 = H_ / 4;                 // 64 float4 per row
constexpr int RPS = 16;                    // source rows per block
constexpr int N_SCAT = S_ / RPS;           // 32 blocks per batch

typedef float f32x4 __attribute__((ext_vector_type(4)));

__global__ __launch_bounds__(256) void lenreg_scatter_kernel(
    const f32x4* __restrict__ x,        // [B,S,64]
    const int* __restrict__ dur,        // [B,S]
    const int* __restrict__ max_len_p,  // [1]
    f32x4* __restrict__ out,            // [B,T,64]
    float* __restrict__ mel_len_out)    // [B]
{
    const int b = blockIdx.y;
    const int role = blockIdx.x;              // 0..31
    const int tid = threadIdx.x;
    const int lane = tid & 63;
    const int wave = tid >> 6;

    __shared__ int s_cum[S_];
    __shared__ int s_wsum[4];
    __shared__ f32x4 s_rows[RPS][F4];         // 16 KB row stage

    const f32x4* __restrict__ x_b = x + (size_t)b * S_ * F4;
    f32x4* __restrict__ out_b = out + (size_t)b * T_ * F4;

    // --- issue x loads FIRST: independent of the scan, overlap latencies ---
    const int s0 = role * RPS;
    const int sw = s0 + wave * (RPS / 4);
    f32x4 v[RPS / 4];
#pragma unroll
    for (int i = 0; i < RPS / 4; ++i)
        v[i] = x_b[(size_t)(sw + i) * F4 + lane];
    const f32x4 vtail = x_b[(size_t)(S_ - 1) * F4 + lane];

    // --- cumsum of dur[b][:]: 2 elems/thread shuffle scan + LDS combine ---
    const int2 d2 = ((const int2*)(dur + b * S_))[tid];
    const int pair = d2.x + d2.y;
    int scan = pair;
#pragma unroll
    for (int off = 1; off < 64; off <<= 1) {
        const int y = __shfl_up(scan, off);
        if (lane >= off) scan += y;
    }
    if (lane == 63) s_wsum[wave] = scan;
    __syncthreads();
    int wprefix = 0;
#pragma unroll
    for (int w = 0; w < 4; ++w) wprefix += (w < wave) ? s_wsum[w] : 0;
    const int excl = wprefix + scan - pair;
    s_cum[2 * tid]     = excl + d2.x;
    s_cum[2 * tid + 1] = excl + pair;

    // --- stage this block's 16 source rows into LDS (waits on x loads) ---
#pragma unroll
    for (int i = 0; i < RPS / 4; ++i)
        s_rows[wave * (RPS / 4) + i][lane] = v[i];
    __syncthreads();

    const int total = s_cum[S_ - 1];

    // --- balanced scatter: block's output range split round-robin by wave ---
    const int lo = s0 ? s_cum[s0 - 1] : 0;
    int hi = s_cum[s0 + RPS - 1];
    if (hi > T_) hi = T_;
    int sp = 0;   // running source-row pointer (monotone in t per wave)
    for (int t = lo + wave; t < hi; t += 4) {
        while (s_cum[s0 + sp] <= t) ++sp;   // first row with cum > t
        __builtin_nontemporal_store(s_rows[sp][lane], &out_b[(size_t)t * F4 + lane]);
    }

    // --- tail: fill [total, T) with row S-1, interleaved across blocks ---
    for (int t = total + role * 4 + wave; t < T_; t += 4 * N_SCAT)
        __builtin_nontemporal_store(vtail, &out_b[(size_t)t * F4 + lane]);

    if (role == 0 && tid == 0) {
        const int ml = max_len_p[0];
        mel_len_out[b] = (float)(total < ml ? total : ml);
    }
}

extern "C" void kernel_launch(void* const* d_in, const int* in_sizes, int n_in,
                              void* d_out, int out_size, void* d_ws, size_t ws_size,
                              hipStream_t stream) {
    const f32x4* x = (const f32x4*)d_in[0];
    const int* duration = (const int*)d_in[1];
    const int* max_len_p = (const int*)d_in[2];

    float* out = (float*)d_out;                        // [B,T,H]
    float* mel_len_out = out + (size_t)B_ * T_ * H_;   // [B] as floats

    dim3 grid(N_SCAT, B_);                             // 32 x 32 = 1024 blocks
    lenreg_scatter_kernel<<<grid, 256, 0, stream>>>(
        x, duration, max_len_p, (f32x4*)out, mel_len_out);
}

// Round 3
// 84.000 us; speedup vs baseline: 1.0308x; 1.0308x over previous
//
#include <hip/hip_runtime.h>

// B=32, S=512, H=256, T=MAX_MEL=2000, DUR_MAX=8 (dur in [0,8))
// d_out: output [B,T,H] f32 then mel_len [B] as floats.
//
// R10: R8 structure (plain stores — R9 A/B showed nt hurts: out-poison is
// L3-resident dirty and our overwrites land in-cache) + INDEX-TABLE scatter:
//  - R8's store loop advanced a source-row pointer with
//    `while (s_cum[..] <= t) ++sp;` — a loop-carried LDS-read chain
//    (~120 cyc/read, single-outstanding) that also blocked store MLP.
//  - R10 materializes the block-local map t -> source row into s_idx[]
//    (16 threads, <=7 LDS writes each), making every store-loop iteration
//    independent: broadcast s_idx read + conflict-free ds_read_b128 + store,
//    unrolled x4 so several 1 KB stores are in flight per wave.
//  Traffic stays compulsory: x read once (16.8 MB), out written once (65.5 MB).
constexpr int B_ = 32;
constexpr int S_ = 512;
constexpr int H_ = 256;
constexpr int T_ = 2000;
constexpr int F4 = H_ / 4;                 // 64 float4 per row
constexpr int RPS = 16;                    // source rows per block
constexpr int N_SCAT = S_ / RPS;           // 32 blocks per batch
constexpr int MAXRANGE = 128;              // >= RPS * (DUR_MAX-1) = 112

typedef float f32x4 __attribute__((ext_vector_type(4)));

__global__ __launch_bounds__(256) void lenreg_scatter_kernel(
    const f32x4* __restrict__ x,        // [B,S,64]
    const int* __restrict__ dur,        // [B,S]
    const int* __restrict__ max_len_p,  // [1]
    f32x4* __restrict__ out,            // [B,T,64]
    float* __restrict__ mel_len_out)    // [B]
{
    const int b = blockIdx.y;
    const int role = blockIdx.x;              // 0..31
    const int tid = threadIdx.x;
    const int lane = tid & 63;
    const int wave = tid >> 6;

    __shared__ int s_cum[S_];
    __shared__ int s_wsum[4];
    __shared__ f32x4 s_rows[RPS][F4];         // 16 KB row stage
    __shared__ unsigned char s_idx[MAXRANGE]; // block-local t -> source row

    const f32x4* __restrict__ x_b = x + (size_t)b * S_ * F4;
    f32x4* __restrict__ out_b = out + (size_t)b * T_ * F4;

    // --- issue x loads FIRST: independent of the scan, overlap latencies ---
    const int s0 = role * RPS;
    const int sw = s0 + wave * (RPS / 4);
    f32x4 v[RPS / 4];
#pragma unroll
    for (int i = 0; i < RPS / 4; ++i)
        v[i] = x_b[(size_t)(sw + i) * F4 + lane];
    const f32x4 vtail = x_b[(size_t)(S_ - 1) * F4 + lane];

    // --- cumsum of dur[b][:]: 2 elems/thread shuffle scan + LDS combine ---
    const int2 d2 = ((const int2*)(dur + b * S_))[tid];
    const int pair = d2.x + d2.y;
    int scan = pair;
#pragma unroll
    for (int off = 1; off < 64; off <<= 1) {
        const int y = __shfl_up(scan, off);
        if (lane >= off) scan += y;
    }
    if (lane == 63) s_wsum[wave] = scan;
    __syncthreads();
    int wprefix = 0;
#pragma unroll
    for (int w = 0; w < 4; ++w) wprefix += (w < wave) ? s_wsum[w] : 0;
    const int excl = wprefix + scan - pair;
    s_cum[2 * tid]     = excl + d2.x;
    s_cum[2 * tid + 1] = excl + pair;

    // --- stage this block's 16 source rows into LDS (waits on x loads) ---
#pragma unroll
    for (int i = 0; i < RPS / 4; ++i)
        s_rows[wave * (RPS / 4) + i][lane] = v[i];
    __syncthreads();

    const int total = s_cum[S_ - 1];
    const int lo = s0 ? s_cum[s0 - 1] : 0;
    int hi = s_cum[s0 + RPS - 1];
    if (hi > T_) hi = T_;

    // --- build block-local index table: s_idx[t - lo] = source row ---
    if (tid < RPS) {
        const int row = s0 + tid;
        const int beg = (row ? s_cum[row - 1] : 0) - lo;
        const int end = s_cum[row] - lo;
        for (int i = beg; i < end; ++i) s_idx[i] = (unsigned char)tid;
    }
    __syncthreads();

    // --- balanced scatter: independent iterations, stores pipelined ---
#pragma unroll 4
    for (int t = lo + wave; t < hi; t += 4)
        out_b[(size_t)t * F4 + lane] = s_rows[s_idx[t - lo]][lane];

    // --- tail: fill [total, T) with row S-1, interleaved across blocks ---
    for (int t = total + role * 4 + wave; t < T_; t += 4 * N_SCAT)
        out_b[(size_t)t * F4 + lane] = vtail;

    if (role == 0 && tid == 0) {
        const int ml = max_len_p[0];
        mel_len_out[b] = (float)(total < ml ? total : ml);
    }
}

extern "C" void kernel_launch(void* const* d_in, const int* in_sizes, int n_in,
                              void* d_out, int out_size, void* d_ws, size_t ws_size,
                              hipStream_t stream) {
    const f32x4* x = (const f32x4*)d_in[0];
    const int* duration = (const int*)d_in[1];
    const int* max_len_p = (const int*)d_in[2];

    float* out = (float*)d_out;                        // [B,T,H]
    float* mel_len_out = out + (size_t)B_ * T_ * H_;   // [B] as floats

    dim3 grid(N_SCAT, B_);                             // 32 x 32 = 1024 blocks
    lenreg_scatter_kernel<<<grid, 256, 0, stream>>>(
        x, duration, max_len_p, (f32x4*)out, mel_len_out);
}